// Round 2
// baseline (952.792 us; speedup 1.0000x reference)
//
#include <hip/hip_runtime.h>

#define DEV __device__ __forceinline__

static const int NN = 100000;
static const int EE = 1000000;

DEV float bf2f(unsigned int h) {
    unsigned int u = h << 16;
    float f;
    __builtin_memcpy(&f, &u, 4);
    return f;
}
DEV unsigned short f2bf(float f) {  // round-to-nearest-even
    unsigned int u;
    __builtin_memcpy(&u, &f, 4);
    u = u + 0x7FFFu + ((u >> 16) & 1u);
    return (unsigned short)(u >> 16);
}
DEV unsigned int pk2(float a, float b) {
    return (unsigned int)f2bf(a) | ((unsigned int)f2bf(b) << 16);
}
DEV void unpack8(uint4 u, float* v) {
    v[0] = bf2f(u.x & 0xffffu); v[1] = bf2f(u.x >> 16);
    v[2] = bf2f(u.y & 0xffffu); v[3] = bf2f(u.y >> 16);
    v[4] = bf2f(u.z & 0xffffu); v[5] = bf2f(u.z >> 16);
    v[6] = bf2f(u.w & 0xffffu); v[7] = bf2f(u.w >> 16);
}
DEV void store_row64(unsigned short* __restrict__ out, int r, const float* acc, bool relu) {
    uint4* o = reinterpret_cast<uint4*>(out + (size_t)r * 64);
#pragma unroll
    for (int c = 0; c < 8; c++) {
        float a[8];
#pragma unroll
        for (int i = 0; i < 8; i++) {
            float x = acc[c * 8 + i];
            a[i] = relu ? fmaxf(x, 0.0f) : x;
        }
        uint4 u;
        u.x = pk2(a[0], a[1]); u.y = pk2(a[2], a[3]);
        u.z = pk2(a[4], a[5]); u.w = pk2(a[6], a[7]);
        o[c] = u;
    }
}

// ---------------- CSR build ----------------
__global__ __launch_bounds__(256) void k_count(const int* __restrict__ dst, int* __restrict__ cnt, int e) {
    int i = blockIdx.x * blockDim.x + threadIdx.x;
    if (i < e) atomicAdd(&cnt[dst[i]], 1);
}
__global__ __launch_bounds__(256) void k_dinv(const int* __restrict__ cnt, float* __restrict__ dinv, int n) {
    int i = blockIdx.x * blockDim.x + threadIdx.x;
    if (i < n) dinv[i] = rsqrtf((float)cnt[i] + 1.0f);
}
__global__ __launch_bounds__(256) void k_scan_partial(const int* __restrict__ cnt, int* __restrict__ partial, int n) {
    __shared__ int lds[256];
    int base = blockIdx.x * 1024;
    int t = threadIdx.x;
    int s = 0;
#pragma unroll
    for (int i = 0; i < 4; i++) {
        int idx = base + t * 4 + i;
        s += (idx < n) ? cnt[idx] : 0;
    }
    lds[t] = s;
    __syncthreads();
    for (int off = 128; off > 0; off >>= 1) {
        if (t < off) lds[t] += lds[t + off];
        __syncthreads();
    }
    if (t == 0) partial[blockIdx.x] = lds[0];
}
__global__ __launch_bounds__(256) void k_scan_single(int* __restrict__ partial, int B) {
    __shared__ int lds[256];
    int t = threadIdx.x;
    int v = (t < B) ? partial[t] : 0;
    lds[t] = v;
    __syncthreads();
    for (int off = 1; off < 256; off <<= 1) {
        int x = (t >= off) ? lds[t - off] : 0;
        __syncthreads();
        lds[t] += x;
        __syncthreads();
    }
    if (t < B) partial[t] = lds[t] - v;  // exclusive
}
__global__ __launch_bounds__(256) void k_scan_write(const int* __restrict__ cnt, const int* __restrict__ partial,
                                                   int* __restrict__ rowptr, int n, int total) {
    __shared__ int lds[256];
    int base = blockIdx.x * 1024;
    int t = threadIdx.x;
    int v[4];
    int s = 0;
#pragma unroll
    for (int i = 0; i < 4; i++) {
        int idx = base + t * 4 + i;
        v[i] = (idx < n) ? cnt[idx] : 0;
        s += v[i];
    }
    lds[t] = s;
    __syncthreads();
    int mine = s;
    for (int off = 1; off < 256; off <<= 1) {
        int x = (t >= off) ? lds[t - off] : 0;
        __syncthreads();
        lds[t] += x;
        __syncthreads();
    }
    int run = lds[t] - mine + partial[blockIdx.x];
#pragma unroll
    for (int i = 0; i < 4; i++) {
        int idx = base + t * 4 + i;
        if (idx < n) rowptr[idx] = run;
        run += v[i];
    }
    if (blockIdx.x == 0 && t == 0) rowptr[n] = total;
}
__global__ __launch_bounds__(256) void k_fill(const int* __restrict__ src, const int* __restrict__ dstv,
                                              const float* __restrict__ dinv, const int* __restrict__ rowptr,
                                              int* __restrict__ cursor, int* __restrict__ col,
                                              float* __restrict__ coef, int e) {
    int i = blockIdx.x * blockDim.x + threadIdx.x;
    if (i >= e) return;
    int s = src[i], d = dstv[i];
    int pos = atomicAdd(&cursor[d], 1);
    int idx = rowptr[d] + pos;
    col[idx] = s;
    coef[idx] = dinv[s] * dinv[d];
}

// ---------------- dense layers ----------------
// (N,4) f32 @ (4,64) + b, relu -> bf16
__global__ __launch_bounds__(256) void k_enc1(const float* __restrict__ x, const float* __restrict__ w,
                                              const float* __restrict__ b, unsigned short* __restrict__ out, int n) {
    int r = blockIdx.x * blockDim.x + threadIdx.x;
    if (r >= n) return;
    float4 xv = reinterpret_cast<const float4*>(x)[r];
    float v[4] = {xv.x, xv.y, xv.z, xv.w};
    float acc[64];
#pragma unroll
    for (int j = 0; j < 64; j++) acc[j] = b[j];
#pragma unroll
    for (int i = 0; i < 4; i++) {
#pragma unroll
        for (int j = 0; j < 64; j++) acc[j] = fmaf(v[i], w[i * 64 + j], acc[j]);
    }
    store_row64(out, r, acc, true);
}

// bf16 (N,64) @ f32 (64,64) [+ bias] [relu] -> bf16
__global__ __launch_bounds__(256) void k_gemm64(const unsigned short* __restrict__ in, const float* __restrict__ w,
                                                const float* __restrict__ bias, unsigned short* __restrict__ out,
                                                int n, int relu) {
    int r = blockIdx.x * blockDim.x + threadIdx.x;
    if (r >= n) return;
    float acc[64];
    if (bias) {
#pragma unroll
        for (int j = 0; j < 64; j++) acc[j] = bias[j];
    } else {
#pragma unroll
        for (int j = 0; j < 64; j++) acc[j] = 0.0f;
    }
    const uint4* inr = reinterpret_cast<const uint4*>(in + (size_t)r * 64);
#pragma unroll 1
    for (int k0 = 0; k0 < 8; k0++) {
        uint4 u = inr[k0];
        float v[8];
        unpack8(u, v);
        const float* wk = w + k0 * 8 * 64;
#pragma unroll
        for (int i = 0; i < 8; i++) {
#pragma unroll
            for (int j = 0; j < 64; j++) acc[j] = fmaf(v[i], wk[i * 64 + j], acc[j]);
        }
    }
    store_row64(out, r, acc, relu != 0);
}

// concat(F,S) bf16 (N,128) @ f32 (128,64) + b, relu -> bf16
__global__ __launch_bounds__(256) void k_fus1(const unsigned short* __restrict__ F, const unsigned short* __restrict__ S,
                                              const float* __restrict__ w, const float* __restrict__ b,
                                              unsigned short* __restrict__ out, int n) {
    int r = blockIdx.x * blockDim.x + threadIdx.x;
    if (r >= n) return;
    float acc[64];
#pragma unroll
    for (int j = 0; j < 64; j++) acc[j] = b[j];
    const uint4* Fr = reinterpret_cast<const uint4*>(F + (size_t)r * 64);
    const uint4* Sr = reinterpret_cast<const uint4*>(S + (size_t)r * 64);
#pragma unroll 1
    for (int k0 = 0; k0 < 8; k0++) {
        uint4 u = Fr[k0];
        float v[8];
        unpack8(u, v);
        const float* wk = w + k0 * 8 * 64;
#pragma unroll
        for (int i = 0; i < 8; i++) {
#pragma unroll
            for (int j = 0; j < 64; j++) acc[j] = fmaf(v[i], wk[i * 64 + j], acc[j]);
        }
    }
#pragma unroll 1
    for (int k0 = 0; k0 < 8; k0++) {
        uint4 u = Sr[k0];
        float v[8];
        unpack8(u, v);
        const float* wk = w + (64 + k0 * 8) * 64;
#pragma unroll
        for (int i = 0; i < 8; i++) {
#pragma unroll
            for (int j = 0; j < 64; j++) acc[j] = fmaf(v[i], wk[i * 64 + j], acc[j]);
        }
    }
    store_row64(out, r, acc, true);
}

// heads: fused bf16 (N,64) @ out_w(64,32)+ob  and @ cls_w(64,2)+cb -> f32 d_out
__global__ __launch_bounds__(256) void k_heads(const unsigned short* __restrict__ fused, const float* __restrict__ ow,
                                               const float* __restrict__ ob, const float* __restrict__ cw,
                                               const float* __restrict__ cb, float* __restrict__ out, int n) {
    int r = blockIdx.x * blockDim.x + threadIdx.x;
    if (r >= n) return;
    float nf[32];
#pragma unroll
    for (int j = 0; j < 32; j++) nf[j] = ob[j];
    float nt0 = cb[0], nt1 = cb[1];
    const uint4* fr = reinterpret_cast<const uint4*>(fused + (size_t)r * 64);
#pragma unroll 1
    for (int k0 = 0; k0 < 8; k0++) {
        uint4 u = fr[k0];
        float v[8];
        unpack8(u, v);
#pragma unroll
        for (int i = 0; i < 8; i++) {
            int k = k0 * 8 + i;
#pragma unroll
            for (int j = 0; j < 32; j++) nf[j] = fmaf(v[i], ow[k * 32 + j], nf[j]);
            nt0 = fmaf(v[i], cw[k * 2 + 0], nt0);
            nt1 = fmaf(v[i], cw[k * 2 + 1], nt1);
        }
    }
    float4* o = reinterpret_cast<float4*>(out + (size_t)r * 32);
#pragma unroll
    for (int c = 0; c < 8; c++) {
        o[c] = make_float4(nf[c * 4 + 0], nf[c * 4 + 1], nf[c * 4 + 2], nf[c * 4 + 3]);
    }
    float2* o2 = reinterpret_cast<float2*>(out + (size_t)NN * 32);
    o2[r] = make_float2(nt0, nt1);
}

// ---------------- GCN aggregation (pull, no atomics) ----------------
// 8 lanes per node, 8 features per lane. out = relu(agg + xw*dinv^2 + b)
__global__ __launch_bounds__(256) void k_gather(const unsigned short* __restrict__ xw, const int* __restrict__ rowptr,
                                                const int* __restrict__ col, const float* __restrict__ coef,
                                                const float* __restrict__ dinv, const float* __restrict__ bias,
                                                unsigned short* __restrict__ out, int n) {
    int gid = blockIdx.x * blockDim.x + threadIdx.x;
    int node = gid >> 3;
    int lane = gid & 7;
    if (node >= n) return;
    int fbase = lane * 8;
    float d = dinv[node];
    float d2 = d * d;
    float acc[8];
    {
        uint4 su = *reinterpret_cast<const uint4*>(xw + (size_t)node * 64 + fbase);
        float sv[8];
        unpack8(su, sv);
#pragma unroll
        for (int i = 0; i < 8; i++) acc[i] = fmaf(sv[i], d2, bias[fbase + i]);
    }
    int e0 = rowptr[node], e1 = rowptr[node + 1];
    for (int e = e0; e < e1; e++) {
        int s = col[e];
        float c = coef[e];
        uint4 u = *reinterpret_cast<const uint4*>(xw + (size_t)s * 64 + fbase);
        float v[8];
        unpack8(u, v);
#pragma unroll
        for (int i = 0; i < 8; i++) acc[i] = fmaf(v[i], c, acc[i]);
    }
    uint4 ou;
    float a[8];
#pragma unroll
    for (int i = 0; i < 8; i++) a[i] = fmaxf(acc[i], 0.0f);
    ou.x = pk2(a[0], a[1]); ou.y = pk2(a[2], a[3]); ou.z = pk2(a[4], a[5]); ou.w = pk2(a[6], a[7]);
    *reinterpret_cast<uint4*>(out + (size_t)node * 64 + fbase) = ou;
}

extern "C" void kernel_launch(void* const* d_in, const int* in_sizes, int n_in,
                              void* d_out, int out_size, void* d_ws, size_t ws_size,
                              hipStream_t stream) {
    const int N = NN, E = EE;
    const float* front_x = (const float*)d_in[0];
    const float* side_x = (const float*)d_in[1];
    const int* fei = (const int*)d_in[2];
    const int* sei = (const int*)d_in[3];
    const float* fe_enc_w1 = (const float*)d_in[4];
    const float* fe_enc_b1 = (const float*)d_in[5];
    const float* fe_enc_w2 = (const float*)d_in[6];
    const float* fe_enc_b2 = (const float*)d_in[7];
    const float* fe_conv_w = (const float*)d_in[8];
    const float* fe_conv_b = (const float*)d_in[9];
    const float* se_enc_w1 = (const float*)d_in[10];
    const float* se_enc_b1 = (const float*)d_in[11];
    const float* se_enc_w2 = (const float*)d_in[12];
    const float* se_enc_b2 = (const float*)d_in[13];
    const float* se_conv_w = (const float*)d_in[14];
    const float* se_conv_b = (const float*)d_in[15];
    const float* fus_w1 = (const float*)d_in[16];
    const float* fus_b1 = (const float*)d_in[17];
    const float* fus_w2 = (const float*)d_in[18];
    const float* fus_b2 = (const float*)d_in[19];
    const float* out_w = (const float*)d_in[20];
    const float* out_b = (const float*)d_in[21];
    const float* cls_w = (const float*)d_in[22];
    const float* cls_b = (const float*)d_in[23];

    // workspace carve (256B aligned)
    char* ws = (char*)d_ws;
    size_t off = 0;
    auto take = [&](size_t bytes) -> char* {
        char* p = ws + off;
        off = (off + bytes + 255) & ~(size_t)255;
        return p;
    };
    int* cnt = (int*)take((size_t)2 * N * 4);  // cnt, cursor
    int* cur = cnt + N;
    int* rowptr = (int*)take((size_t)(N + 1) * 4);
    float* dinv = (float*)take((size_t)N * 4);
    int* col = (int*)take((size_t)E * 4);
    float* coef = (float*)take((size_t)E * 4);
    int* part = (int*)take(256 * 4);
    unsigned short* A_f = (unsigned short*)take((size_t)N * 64 * 2);
    unsigned short* A_s = (unsigned short*)take((size_t)N * 64 * 2);
    unsigned short* B = (unsigned short*)take((size_t)N * 64 * 2);

    const int NB_ROW = (N + 255) / 256;
    const int NB_E = (E + 255) / 256;
    const int NB_G = (N * 8 + 255) / 256;
    const int SB = (N + 1023) / 1024;

    // ---- front graph CSR ----
    hipMemsetAsync(cnt, 0, (size_t)2 * N * 4, stream);
    k_count<<<NB_E, 256, 0, stream>>>(fei + E, cnt, E);
    k_dinv<<<NB_ROW, 256, 0, stream>>>(cnt, dinv, N);
    k_scan_partial<<<SB, 256, 0, stream>>>(cnt, part, N);
    k_scan_single<<<1, 256, 0, stream>>>(part, SB);
    k_scan_write<<<SB, 256, 0, stream>>>(cnt, part, rowptr, N, E);
    k_fill<<<NB_E, 256, 0, stream>>>(fei, fei + E, dinv, rowptr, cur, col, coef, E);

    // ---- front encoder ----
    k_enc1<<<NB_ROW, 256, 0, stream>>>(front_x, fe_enc_w1, fe_enc_b1, B, N);
    k_gemm64<<<NB_ROW, 256, 0, stream>>>(B, fe_enc_w2, fe_enc_b2, A_f, N, 0);
    for (int l = 0; l < 3; l++) {
        k_gemm64<<<NB_ROW, 256, 0, stream>>>(A_f, fe_conv_w + l * 4096, nullptr, B, N, 0);
        k_gather<<<NB_G, 256, 0, stream>>>(B, rowptr, col, coef, dinv, fe_conv_b + l * 64, A_f, N);
    }

    // ---- side graph CSR (reuse buffers) ----
    hipMemsetAsync(cnt, 0, (size_t)2 * N * 4, stream);
    k_count<<<NB_E, 256, 0, stream>>>(sei + E, cnt, E);
    k_dinv<<<NB_ROW, 256, 0, stream>>>(cnt, dinv, N);
    k_scan_partial<<<SB, 256, 0, stream>>>(cnt, part, N);
    k_scan_single<<<1, 256, 0, stream>>>(part, SB);
    k_scan_write<<<SB, 256, 0, stream>>>(cnt, part, rowptr, N, E);
    k_fill<<<NB_E, 256, 0, stream>>>(sei, sei + E, dinv, rowptr, cur, col, coef, E);

    // ---- side encoder ----
    k_enc1<<<NB_ROW, 256, 0, stream>>>(side_x, se_enc_w1, se_enc_b1, B, N);
    k_gemm64<<<NB_ROW, 256, 0, stream>>>(B, se_enc_w2, se_enc_b2, A_s, N, 0);
    for (int l = 0; l < 3; l++) {
        k_gemm64<<<NB_ROW, 256, 0, stream>>>(A_s, se_conv_w + l * 4096, nullptr, B, N, 0);
        k_gather<<<NB_G, 256, 0, stream>>>(B, rowptr, col, coef, dinv, se_conv_b + l * 64, A_s, N);
    }

    // ---- fusion + heads ----
    k_fus1<<<NB_ROW, 256, 0, stream>>>(A_f, A_s, fus_w1, fus_b1, B, N);
    k_gemm64<<<NB_ROW, 256, 0, stream>>>(B, fus_w2, fus_b2, A_f, N, 0);  // A_f reused as scratch
    k_heads<<<NB_ROW, 256, 0, stream>>>(A_f, out_w, out_b, cls_w, cls_b, (float*)d_out, N);
}

// Round 3
// 847.546 us; speedup vs baseline: 1.1242x; 1.1242x over previous
//
#include <hip/hip_runtime.h>

#define DEV __device__ __forceinline__

static const int NN = 100000;
static const int EE = 1000000;

DEV float bf2f(unsigned int h) {
    unsigned int u = h << 16;
    float f;
    __builtin_memcpy(&f, &u, 4);
    return f;
}
DEV unsigned short f2bf(float f) {  // round-to-nearest-even
    unsigned int u;
    __builtin_memcpy(&u, &f, 4);
    u = u + 0x7FFFu + ((u >> 16) & 1u);
    return (unsigned short)(u >> 16);
}
DEV unsigned int pk2(float a, float b) {
    return (unsigned int)f2bf(a) | ((unsigned int)f2bf(b) << 16);
}
DEV void unpack8(uint4 u, float* v) {
    v[0] = bf2f(u.x & 0xffffu); v[1] = bf2f(u.x >> 16);
    v[2] = bf2f(u.y & 0xffffu); v[3] = bf2f(u.y >> 16);
    v[4] = bf2f(u.z & 0xffffu); v[5] = bf2f(u.z >> 16);
    v[6] = bf2f(u.w & 0xffffu); v[7] = bf2f(u.w >> 16);
}
DEV void store_row64(unsigned short* __restrict__ out, int r, const float* acc, bool relu) {
    uint4* o = reinterpret_cast<uint4*>(out + (size_t)r * 64);
#pragma unroll
    for (int c = 0; c < 8; c++) {
        float a[8];
#pragma unroll
        for (int i = 0; i < 8; i++) {
            float x = acc[c * 8 + i];
            a[i] = relu ? fmaxf(x, 0.0f) : x;
        }
        uint4 u;
        u.x = pk2(a[0], a[1]); u.y = pk2(a[2], a[3]);
        u.z = pk2(a[4], a[5]); u.w = pk2(a[6], a[7]);
        o[c] = u;
    }
}

// ---------------- CSR build (dual-graph via blockIdx.y) ----------------
__global__ __launch_bounds__(256) void k_count_dual(const int* __restrict__ d0, const int* __restrict__ d1,
                                                    int* __restrict__ c0, int* __restrict__ c1, int e) {
    int g = blockIdx.y;
    const int* dst = g ? d1 : d0;
    int* cnt = g ? c1 : c0;
    int i = blockIdx.x * blockDim.x + threadIdx.x;
    if (i < e) atomicAdd(&cnt[dst[i]], 1);
}
__global__ __launch_bounds__(256) void k_dinv_dual(const int* __restrict__ c0, const int* __restrict__ c1,
                                                   float* __restrict__ v0, float* __restrict__ v1, int n) {
    int g = blockIdx.y;
    const int* cnt = g ? c1 : c0;
    float* dinv = g ? v1 : v0;
    int i = blockIdx.x * blockDim.x + threadIdx.x;
    if (i < n) dinv[i] = rsqrtf((float)cnt[i] + 1.0f);
}
__global__ __launch_bounds__(256) void k_scan_partial_dual(const int* __restrict__ c0, const int* __restrict__ c1,
                                                           int* __restrict__ p0, int* __restrict__ p1, int n) {
    int g = blockIdx.y;
    const int* cnt = g ? c1 : c0;
    int* partial = g ? p1 : p0;
    __shared__ int lds[256];
    int base = blockIdx.x * 1024;
    int t = threadIdx.x;
    int s = 0;
#pragma unroll
    for (int i = 0; i < 4; i++) {
        int idx = base + t * 4 + i;
        s += (idx < n) ? cnt[idx] : 0;
    }
    lds[t] = s;
    __syncthreads();
    for (int off = 128; off > 0; off >>= 1) {
        if (t < off) lds[t] += lds[t + off];
        __syncthreads();
    }
    if (t == 0) partial[blockIdx.x] = lds[0];
}
__global__ __launch_bounds__(256) void k_scan_single_dual(int* __restrict__ p0, int* __restrict__ p1, int B) {
    int g = blockIdx.y;
    int* partial = g ? p1 : p0;
    __shared__ int lds[256];
    int t = threadIdx.x;
    int v = (t < B) ? partial[t] : 0;
    lds[t] = v;
    __syncthreads();
    for (int off = 1; off < 256; off <<= 1) {
        int x = (t >= off) ? lds[t - off] : 0;
        __syncthreads();
        lds[t] += x;
        __syncthreads();
    }
    if (t < B) partial[t] = lds[t] - v;  // exclusive
}
__global__ __launch_bounds__(256) void k_scan_write_dual(const int* __restrict__ c0, const int* __restrict__ c1,
                                                         const int* __restrict__ p0, const int* __restrict__ p1,
                                                         int* __restrict__ r0, int* __restrict__ r1,
                                                         int n, int total) {
    int g = blockIdx.y;
    const int* cnt = g ? c1 : c0;
    const int* partial = g ? p1 : p0;
    int* rowptr = g ? r1 : r0;
    __shared__ int lds[256];
    int base = blockIdx.x * 1024;
    int t = threadIdx.x;
    int v[4];
    int s = 0;
#pragma unroll
    for (int i = 0; i < 4; i++) {
        int idx = base + t * 4 + i;
        v[i] = (idx < n) ? cnt[idx] : 0;
        s += v[i];
    }
    lds[t] = s;
    __syncthreads();
    int mine = s;
    for (int off = 1; off < 256; off <<= 1) {
        int x = (t >= off) ? lds[t - off] : 0;
        __syncthreads();
        lds[t] += x;
        __syncthreads();
    }
    int run = lds[t] - mine + partial[blockIdx.x];
#pragma unroll
    for (int i = 0; i < 4; i++) {
        int idx = base + t * 4 + i;
        if (idx < n) rowptr[idx] = run;
        run += v[i];
    }
    if (blockIdx.x == 0 && t == 0) rowptr[n] = total;
}
// packed edge record: .x = src node, .y = bit-pattern of coef
__global__ __launch_bounds__(256) void k_fill_dual(const int* __restrict__ s0, const int* __restrict__ s1,
                                                   const float* __restrict__ v0, const float* __restrict__ v1,
                                                   const int* __restrict__ r0, const int* __restrict__ r1,
                                                   int* __restrict__ u0, int* __restrict__ u1,
                                                   int2* __restrict__ e0, int2* __restrict__ e1, int e) {
    int g = blockIdx.y;
    const int* src = g ? s1 : s0;
    const int* dstv = src + e;
    const float* dinv = g ? v1 : v0;
    const int* rowptr = g ? r1 : r0;
    int* cursor = g ? u1 : u0;
    int2* ec = g ? e1 : e0;
    int i = blockIdx.x * blockDim.x + threadIdx.x;
    if (i >= e) return;
    int s = src[i], d = dstv[i];
    int pos = atomicAdd(&cursor[d], 1);
    int idx = rowptr[d] + pos;
    ec[idx] = make_int2(s, __float_as_int(dinv[s] * dinv[d]));
}

// ---------------- dense layers ----------------
// (N,4) f32 @ (4,64) + b, relu -> bf16   (dual)
__global__ __launch_bounds__(256) void k_enc1_dual(const float* __restrict__ x0, const float* __restrict__ x1,
                                                   const float* __restrict__ w0, const float* __restrict__ w1,
                                                   const float* __restrict__ b0, const float* __restrict__ b1,
                                                   unsigned short* __restrict__ y0, unsigned short* __restrict__ y1,
                                                   int n) {
    int g = blockIdx.y;
    const float* x = g ? x1 : x0;
    const float* w = g ? w1 : w0;
    const float* b = g ? b1 : b0;
    unsigned short* out = g ? y1 : y0;
    int r = blockIdx.x * blockDim.x + threadIdx.x;
    if (r >= n) return;
    float4 xv = reinterpret_cast<const float4*>(x)[r];
    float v[4] = {xv.x, xv.y, xv.z, xv.w};
    float acc[64];
#pragma unroll
    for (int j = 0; j < 64; j++) acc[j] = b[j];
#pragma unroll
    for (int i = 0; i < 4; i++) {
#pragma unroll
        for (int j = 0; j < 64; j++) acc[j] = fmaf(v[i], w[i * 64 + j], acc[j]);
    }
    store_row64(out, r, acc, true);
}

// bf16 (N,64) @ f32 (64,64) [+bias] [relu] -> bf16  (dual)
__global__ __launch_bounds__(256) void k_gemm64_dual(const unsigned short* __restrict__ i0,
                                                     const unsigned short* __restrict__ i1,
                                                     const float* __restrict__ w0, const float* __restrict__ w1,
                                                     const float* __restrict__ b0, const float* __restrict__ b1,
                                                     unsigned short* __restrict__ y0, unsigned short* __restrict__ y1,
                                                     int n, int relu) {
    int g = blockIdx.y;
    const unsigned short* in = g ? i1 : i0;
    const float* w = g ? w1 : w0;
    const float* bias = g ? b1 : b0;
    unsigned short* out = g ? y1 : y0;
    int r = blockIdx.x * blockDim.x + threadIdx.x;
    if (r >= n) return;
    float acc[64];
    if (bias) {
#pragma unroll
        for (int j = 0; j < 64; j++) acc[j] = bias[j];
    } else {
#pragma unroll
        for (int j = 0; j < 64; j++) acc[j] = 0.0f;
    }
    const uint4* inr = reinterpret_cast<const uint4*>(in + (size_t)r * 64);
#pragma unroll 1
    for (int k0 = 0; k0 < 8; k0++) {
        uint4 u = inr[k0];
        float v[8];
        unpack8(u, v);
        const float* wk = w + k0 * 8 * 64;
#pragma unroll
        for (int i = 0; i < 8; i++) {
#pragma unroll
            for (int j = 0; j < 64; j++) acc[j] = fmaf(v[i], wk[i * 64 + j], acc[j]);
        }
    }
    store_row64(out, r, acc, relu != 0);
}

// ---------------- fused GCN layer: y = relu( (A_hat x) W + b )  (dual) ----------------
// phase 1: 8 lanes/node aggregate A_hat x into LDS (f32)
// phase 2: same threads multiply aggregated row by W (64x64), relu, store bf16
__global__ __launch_bounds__(256) void k_conv_dual(const unsigned short* __restrict__ x0,
                                                   const unsigned short* __restrict__ x1,
                                                   const int2* __restrict__ ec0, const int2* __restrict__ ec1,
                                                   const int* __restrict__ r0, const int* __restrict__ r1,
                                                   const float* __restrict__ v0, const float* __restrict__ v1,
                                                   const float* __restrict__ w0, const float* __restrict__ w1,
                                                   const float* __restrict__ b0, const float* __restrict__ b1,
                                                   unsigned short* __restrict__ y0, unsigned short* __restrict__ y1,
                                                   int n) {
    int g = blockIdx.y;
    const unsigned short* x = g ? x1 : x0;
    const int2* ec = g ? ec1 : ec0;
    const int* rowptr = g ? r1 : r0;
    const float* dinv = g ? v1 : v0;
    const float* w = g ? w1 : w0;
    const float* b = g ? b1 : b0;
    unsigned short* y = g ? y1 : y0;

    __shared__ float agg[32][68];  // pad 64->68: phase-2 reads conflict-free

    int t = threadIdx.x;
    int cl = t >> 3;   // local node 0..31
    int ln = t & 7;    // feature-octet lane
    int node = blockIdx.x * 32 + cl;
    int fbase = ln * 8;
    float acc[8];
    if (node < n) {
        float d = dinv[node];
        float d2 = d * d;
        uint4 su = *reinterpret_cast<const uint4*>(x + (size_t)node * 64 + fbase);
        float sv[8];
        unpack8(su, sv);
#pragma unroll
        for (int i = 0; i < 8; i++) acc[i] = sv[i] * d2;
        int e0 = rowptr[node], e1 = rowptr[node + 1];
        for (int e = e0; e < e1; e++) {
            int2 m = ec[e];
            float c = __int_as_float(m.y);
            uint4 u = *reinterpret_cast<const uint4*>(x + (size_t)m.x * 64 + fbase);
            float v[8];
            unpack8(u, v);
#pragma unroll
            for (int i = 0; i < 8; i++) acc[i] = fmaf(v[i], c, acc[i]);
        }
    } else {
#pragma unroll
        for (int i = 0; i < 8; i++) acc[i] = 0.0f;
    }
#pragma unroll
    for (int i = 0; i < 8; i += 4) {
        *reinterpret_cast<float4*>(&agg[cl][fbase + i]) = make_float4(acc[i], acc[i + 1], acc[i + 2], acc[i + 3]);
    }
    __syncthreads();
    if (node >= n) return;

    // phase 2: out[fbase..fbase+8) = b + sum_k agg[cl][k] * W[k][fbase..]
    float out[8];
#pragma unroll
    for (int i = 0; i < 8; i++) out[i] = b[fbase + i];
#pragma unroll 4
    for (int k4 = 0; k4 < 16; k4++) {
        float4 av = *reinterpret_cast<const float4*>(&agg[cl][k4 * 4]);
        float a[4] = {av.x, av.y, av.z, av.w};
#pragma unroll
        for (int kk = 0; kk < 4; kk++) {
            const float4* wr = reinterpret_cast<const float4*>(w + (k4 * 4 + kk) * 64 + fbase);
            float4 wv0 = wr[0], wv1 = wr[1];
            out[0] = fmaf(a[kk], wv0.x, out[0]);
            out[1] = fmaf(a[kk], wv0.y, out[1]);
            out[2] = fmaf(a[kk], wv0.z, out[2]);
            out[3] = fmaf(a[kk], wv0.w, out[3]);
            out[4] = fmaf(a[kk], wv1.x, out[4]);
            out[5] = fmaf(a[kk], wv1.y, out[5]);
            out[6] = fmaf(a[kk], wv1.z, out[6]);
            out[7] = fmaf(a[kk], wv1.w, out[7]);
        }
    }
    uint4 ou;
    float r[8];
#pragma unroll
    for (int i = 0; i < 8; i++) r[i] = fmaxf(out[i], 0.0f);
    ou.x = pk2(r[0], r[1]); ou.y = pk2(r[2], r[3]); ou.z = pk2(r[4], r[5]); ou.w = pk2(r[6], r[7]);
    *reinterpret_cast<uint4*>(y + (size_t)node * 64 + fbase) = ou;
}

// concat(F,S) bf16 (N,128) @ f32 (128,64) + b, relu -> bf16
__global__ __launch_bounds__(256) void k_fus1(const unsigned short* __restrict__ F, const unsigned short* __restrict__ S,
                                              const float* __restrict__ w, const float* __restrict__ b,
                                              unsigned short* __restrict__ out, int n) {
    int r = blockIdx.x * blockDim.x + threadIdx.x;
    if (r >= n) return;
    float acc[64];
#pragma unroll
    for (int j = 0; j < 64; j++) acc[j] = b[j];
    const uint4* Fr = reinterpret_cast<const uint4*>(F + (size_t)r * 64);
    const uint4* Sr = reinterpret_cast<const uint4*>(S + (size_t)r * 64);
#pragma unroll 1
    for (int k0 = 0; k0 < 8; k0++) {
        uint4 u = Fr[k0];
        float v[8];
        unpack8(u, v);
        const float* wk = w + k0 * 8 * 64;
#pragma unroll
        for (int i = 0; i < 8; i++) {
#pragma unroll
            for (int j = 0; j < 64; j++) acc[j] = fmaf(v[i], wk[i * 64 + j], acc[j]);
        }
    }
#pragma unroll 1
    for (int k0 = 0; k0 < 8; k0++) {
        uint4 u = Sr[k0];
        float v[8];
        unpack8(u, v);
        const float* wk = w + (64 + k0 * 8) * 64;
#pragma unroll
        for (int i = 0; i < 8; i++) {
#pragma unroll
            for (int j = 0; j < 64; j++) acc[j] = fmaf(v[i], wk[i * 64 + j], acc[j]);
        }
    }
    store_row64(out, r, acc, true);
}

// heads: fused bf16 (N,64) @ out_w(64,32)+ob  and @ cls_w(64,2)+cb -> f32 d_out
__global__ __launch_bounds__(256) void k_heads(const unsigned short* __restrict__ fused, const float* __restrict__ ow,
                                               const float* __restrict__ ob, const float* __restrict__ cw,
                                               const float* __restrict__ cb, float* __restrict__ out, int n) {
    int r = blockIdx.x * blockDim.x + threadIdx.x;
    if (r >= n) return;
    float nf[32];
#pragma unroll
    for (int j = 0; j < 32; j++) nf[j] = ob[j];
    float nt0 = cb[0], nt1 = cb[1];
    const uint4* fr = reinterpret_cast<const uint4*>(fused + (size_t)r * 64);
#pragma unroll 1
    for (int k0 = 0; k0 < 8; k0++) {
        uint4 u = fr[k0];
        float v[8];
        unpack8(u, v);
#pragma unroll
        for (int i = 0; i < 8; i++) {
            int k = k0 * 8 + i;
#pragma unroll
            for (int j = 0; j < 32; j++) nf[j] = fmaf(v[i], ow[k * 32 + j], nf[j]);
            nt0 = fmaf(v[i], cw[k * 2 + 0], nt0);
            nt1 = fmaf(v[i], cw[k * 2 + 1], nt1);
        }
    }
    float4* o = reinterpret_cast<float4*>(out + (size_t)r * 32);
#pragma unroll
    for (int c = 0; c < 8; c++) {
        o[c] = make_float4(nf[c * 4 + 0], nf[c * 4 + 1], nf[c * 4 + 2], nf[c * 4 + 3]);
    }
    float2* o2 = reinterpret_cast<float2*>(out + (size_t)NN * 32);
    o2[r] = make_float2(nt0, nt1);
}

extern "C" void kernel_launch(void* const* d_in, const int* in_sizes, int n_in,
                              void* d_out, int out_size, void* d_ws, size_t ws_size,
                              hipStream_t stream) {
    const int N = NN, E = EE;
    const float* front_x = (const float*)d_in[0];
    const float* side_x = (const float*)d_in[1];
    const int* fei = (const int*)d_in[2];
    const int* sei = (const int*)d_in[3];
    const float* fe_enc_w1 = (const float*)d_in[4];
    const float* fe_enc_b1 = (const float*)d_in[5];
    const float* fe_enc_w2 = (const float*)d_in[6];
    const float* fe_enc_b2 = (const float*)d_in[7];
    const float* fe_conv_w = (const float*)d_in[8];
    const float* fe_conv_b = (const float*)d_in[9];
    const float* se_enc_w1 = (const float*)d_in[10];
    const float* se_enc_b1 = (const float*)d_in[11];
    const float* se_enc_w2 = (const float*)d_in[12];
    const float* se_enc_b2 = (const float*)d_in[13];
    const float* se_conv_w = (const float*)d_in[14];
    const float* se_conv_b = (const float*)d_in[15];
    const float* fus_w1 = (const float*)d_in[16];
    const float* fus_b1 = (const float*)d_in[17];
    const float* fus_w2 = (const float*)d_in[18];
    const float* fus_b2 = (const float*)d_in[19];
    const float* out_w = (const float*)d_in[20];
    const float* out_b = (const float*)d_in[21];
    const float* cls_w = (const float*)d_in[22];
    const float* cls_b = (const float*)d_in[23];

    // workspace carve (256B aligned)
    char* ws = (char*)d_ws;
    size_t off = 0;
    auto take = [&](size_t bytes) -> char* {
        char* p = ws + off;
        off = (off + bytes + 255) & ~(size_t)255;
        return p;
    };
    int* zb = (int*)take((size_t)4 * N * 4);  // cnt0,cur0,cnt1,cur1
    int* cnt0 = zb;
    int* cur0 = zb + N;
    int* cnt1 = zb + 2 * N;
    int* cur1 = zb + 3 * N;
    int* rp0 = (int*)take((size_t)(N + 1) * 4);
    int* rp1 = (int*)take((size_t)(N + 1) * 4);
    float* dv0 = (float*)take((size_t)N * 4);
    float* dv1 = (float*)take((size_t)N * 4);
    int* part0 = (int*)take(256 * 4);
    int* part1 = (int*)take(256 * 4);
    int2* ec0 = (int2*)take((size_t)E * 8);
    int2* ec1 = (int2*)take((size_t)E * 8);
    unsigned short* P0 = (unsigned short*)take((size_t)N * 64 * 2);
    unsigned short* P1 = (unsigned short*)take((size_t)N * 64 * 2);
    unsigned short* Q0 = (unsigned short*)take((size_t)N * 64 * 2);
    unsigned short* Q1 = (unsigned short*)take((size_t)N * 64 * 2);

    const int NB_ROW = (N + 255) / 256;
    const int NB_E = (E + 255) / 256;
    const int NB_C = (N + 31) / 32;
    const int SB = (N + 1023) / 1024;

    // ---- CSR build for both graphs ----
    hipMemsetAsync(zb, 0, (size_t)4 * N * 4, stream);
    k_count_dual<<<dim3(NB_E, 2), 256, 0, stream>>>(fei + E, sei + E, cnt0, cnt1, E);
    k_dinv_dual<<<dim3(NB_ROW, 2), 256, 0, stream>>>(cnt0, cnt1, dv0, dv1, N);
    k_scan_partial_dual<<<dim3(SB, 2), 256, 0, stream>>>(cnt0, cnt1, part0, part1, N);
    k_scan_single_dual<<<dim3(1, 2), 256, 0, stream>>>(part0, part1, SB);
    k_scan_write_dual<<<dim3(SB, 2), 256, 0, stream>>>(cnt0, cnt1, part0, part1, rp0, rp1, N, E);
    k_fill_dual<<<dim3(NB_E, 2), 256, 0, stream>>>(fei, sei, dv0, dv1, rp0, rp1, cur0, cur1, ec0, ec1, E);

    // ---- encoders (dual) ----
    k_enc1_dual<<<dim3(NB_ROW, 2), 256, 0, stream>>>(front_x, side_x, fe_enc_w1, se_enc_w1,
                                                     fe_enc_b1, se_enc_b1, P0, P1, N);
    k_gemm64_dual<<<dim3(NB_ROW, 2), 256, 0, stream>>>(P0, P1, fe_enc_w2, se_enc_w2,
                                                       fe_enc_b2, se_enc_b2, Q0, Q1, N, 0);
    // ---- 3 fused conv layers (dual):  Q->P->Q->P ----
    k_conv_dual<<<dim3(NB_C, 2), 256, 0, stream>>>(Q0, Q1, ec0, ec1, rp0, rp1, dv0, dv1,
                                                   fe_conv_w + 0 * 4096, se_conv_w + 0 * 4096,
                                                   fe_conv_b + 0 * 64, se_conv_b + 0 * 64, P0, P1, N);
    k_conv_dual<<<dim3(NB_C, 2), 256, 0, stream>>>(P0, P1, ec0, ec1, rp0, rp1, dv0, dv1,
                                                   fe_conv_w + 1 * 4096, se_conv_w + 1 * 4096,
                                                   fe_conv_b + 1 * 64, se_conv_b + 1 * 64, Q0, Q1, N);
    k_conv_dual<<<dim3(NB_C, 2), 256, 0, stream>>>(Q0, Q1, ec0, ec1, rp0, rp1, dv0, dv1,
                                                   fe_conv_w + 2 * 4096, se_conv_w + 2 * 4096,
                                                   fe_conv_b + 2 * 64, se_conv_b + 2 * 64, P0, P1, N);

    // ---- fusion + heads ----
    k_fus1<<<NB_ROW, 256, 0, stream>>>(P0, P1, fus_w1, fus_b1, Q0, N);
    k_gemm64_dual<<<dim3(NB_ROW, 1), 256, 0, stream>>>(Q0, Q0, fus_w2, fus_w2, fus_b2, fus_b2, Q1, Q1, N, 0);
    k_heads<<<NB_ROW, 256, 0, stream>>>(Q1, out_w, out_b, cls_w, cls_b, (float*)d_out, N);
}